// Round 3
// baseline (694.435 us; speedup 1.0000x reference)
//
#include <hip/hip_runtime.h>
#include <hip/hip_cooperative_groups.h>

namespace cg = cooperative_groups;

#define NEG_SLOPE 0.2f

static const int B = 4, N = 50000, R = 100000, E = 1600000;
static const int X2_CAP = 4096;     // x2 edge list capacity (expected ~64)
static const int R2_CAP = 4096;     // distinct t2 rows (expected ~64)
static const int N1_CAP = 4096;     // n1 slots (expected ~1k)
static const int WDEG  = 64;        // dense w-CSR slab per R-row (mean deg 16)
static const int WIDEG = 96;        // dense wi-CSR slab per n1-slot (mean deg 32)
static const int RBW = 3200;        // bit-words for R rows (100000/32 = 3125)
static const int NBW = 1600;        // bit-words for N nodes (50000/32 = 1563)
static const int ZWORDS = R + N + RBW + RBW + NBW + 8;   // contiguous zero block

struct KParams {
    const int4*  w_rows4;  const int* w_cols;  const float* w_val;
    const int4*  wi_rows4; const int* wi_cols; const float* wi_val;
    const float* x;  const float* W1; const float* diag1;
    const float* W2; const float* diag2;
    const float* rw1; const float* rb1; const float* rw2; const float* rb2;
    float* out;
    float* t1;      // [R][B][32] (t1_raw = W.X rows; later aliased as t2 [r][64])
    float* h2;      // [N][B][16]
    int* w_cnt; int* wi_cnt;
    unsigned* bitsR1; unsigned* bitsR2; unsigned* bitsN1;
    int* tails;     // [0]=x2tail [1]=r2tail [2]=n1tail [3]=r1tail
    int* n1slot; int* n1list; int* r1list; int* r2list;
    int2* x2list; int2* w_pairsD; int2* wi_pairsD;
    int e4;
};

union SMem {
    struct { int lcount; int gbase; int buf[1024]; } comp;     // P2/P3 compaction
    struct { float W1s[1024]; float W2s[512];
             float uls[8][128]; float x1ls[8][128]; } p6;       // 14.3 KB
    struct { float red0[4][64]; float red1[4][64]; float xs[2][64]; } p8;
};

__global__ void __launch_bounds__(256, 4) fused(KParams P) {
    cg::grid_group grid = cg::this_grid();
    const int tid  = threadIdx.x;
    const int gtid = blockIdx.x * blockDim.x + tid;
    const int T    = gridDim.x * blockDim.x;
    const int lane = tid & 63;
    __shared__ SMem sm;

    // ---------------- P0: zero counters/flags/tails ----------------
    for (int i = gtid; i < ZWORDS; i += T) P.w_cnt[i] = 0;   // contiguous block
    grid.sync();

    // ---------------- P1: markA (wi edges from output nodes) ----------------
    for (int i = gtid; i < P.e4; i += T) {
        int4 r = P.wi_rows4[i];
        int rr[4] = {r.x, r.y, r.z, r.w};
#pragma unroll
        for (int j = 0; j < 4; ++j) {
            if (rr[j] >= N - 2) {
                int ed = i * 4 + j;
                int col = P.wi_cols[ed];
                unsigned old = atomicOr(&P.bitsR1[col >> 5], 1u << (col & 31));
                if (!((old >> (col & 31)) & 1u)) {
                    int p = atomicAdd(&P.tails[1], 1);
                    if (p < R2_CAP) P.r2list[p] = col;
                }
                int pos = atomicAdd(&P.tails[0], 1);
                if (pos < X2_CAP)
                    P.x2list[pos] = make_int2(col * 2 + (rr[j] - (N - 2)),
                                              __float_as_int(P.wi_val[ed]));
            }
        }
    }
    grid.sync();

    // ---------------- P2: markB (w edges with bitsR1 row -> n1 set) ----------------
    if (tid == 0) sm.comp.lcount = 0;
    __syncthreads();
    {
        int niter = (P.e4 + T - 1) / T;     // uniform trip count (ballot-safe)
        for (int it = 0; it < niter; ++it) {
            int i = it * T + gtid;
            int4 r = make_int4(-1, -1, -1, -1);
            if (i < P.e4) r = P.w_rows4[i];
            int rr[4] = {r.x, r.y, r.z, r.w};
            unsigned fb[4];
#pragma unroll
            for (int j = 0; j < 4; ++j)
                fb[j] = (rr[j] >= 0) ? ((P.bitsR1[rr[j] >> 5] >> (rr[j] & 31)) & 1u) : 0u;
#pragma unroll
            for (int j = 0; j < 4; ++j) {
                bool isnew = false;
                int c = 0;
                if (fb[j]) {
                    c = P.w_cols[i * 4 + j];
                    unsigned old = atomicOr(&P.bitsN1[c >> 5], 1u << (c & 31));
                    isnew = ((old >> (c & 31)) & 1u) == 0u;
                }
                unsigned long long m = __ballot(isnew);
                if (m) {
                    int leader = __ffsll(m) - 1;
                    int b0 = 0;
                    if (lane == leader) b0 = atomicAdd(&sm.comp.lcount, __popcll(m));
                    b0 = __shfl(b0, leader);
                    if (isnew) {
                        int p = b0 + __popcll(m & ((1ull << lane) - 1));
                        if (p < 1024) sm.comp.buf[p] = c;
                    }
                }
            }
        }
    }
    __syncthreads();
    {
        int lc = sm.comp.lcount; if (lc > 1024) lc = 1024;
        if (tid == 0) sm.comp.gbase = atomicAdd(&P.tails[2], lc);
        __syncthreads();
        for (int t = tid; t < lc; t += 256) {
            int n = sm.comp.buf[t];
            int slot = sm.comp.gbase + t;
            if (slot < N1_CAP) { P.n1list[slot] = n; P.n1slot[n] = slot; }
        }
    }
    grid.sync();

    // ------- P3: markC (wi edges with bitsN1 row): wi place + bitsR2/r1list -------
    if (tid == 0) sm.comp.lcount = 0;
    __syncthreads();
    {
        int niter = (P.e4 + T - 1) / T;
        for (int it = 0; it < niter; ++it) {
            int i = it * T + gtid;
            int4 r = make_int4(-1, -1, -1, -1);
            if (i < P.e4) r = P.wi_rows4[i];
            int rr[4] = {r.x, r.y, r.z, r.w};
            unsigned fb[4];
#pragma unroll
            for (int j = 0; j < 4; ++j)
                fb[j] = (rr[j] >= 0) ? ((P.bitsN1[rr[j] >> 5] >> (rr[j] & 31)) & 1u) : 0u;
#pragma unroll
            for (int j = 0; j < 4; ++j) {
                bool isnew = false;
                int col = 0;
                if (fb[j]) {
                    int ed = i * 4 + j;
                    col = P.wi_cols[ed];
                    float cf = P.wi_val[ed] * P.diag1[col];
                    int slot = P.n1slot[rr[j]];
                    int pos = atomicAdd(&P.wi_cnt[rr[j]], 1);
                    if (slot < N1_CAP && pos < WIDEG)
                        P.wi_pairsD[(size_t)slot * WIDEG + pos] =
                            make_int2(col, __float_as_int(cf));
                    unsigned old = atomicOr(&P.bitsR2[col >> 5], 1u << (col & 31));
                    isnew = ((old >> (col & 31)) & 1u) == 0u;
                }
                unsigned long long m2 = __ballot(isnew);
                if (m2) {
                    int leader = __ffsll(m2) - 1;
                    int b0 = 0;
                    if (lane == leader) b0 = atomicAdd(&sm.comp.lcount, __popcll(m2));
                    b0 = __shfl(b0, leader);
                    if (isnew) {
                        int p = b0 + __popcll(m2 & ((1ull << lane) - 1));
                        if (p < 1024) sm.comp.buf[p] = col;
                    }
                }
            }
        }
    }
    __syncthreads();
    {
        int lc = sm.comp.lcount; if (lc > 1024) lc = 1024;
        if (tid == 0) sm.comp.gbase = atomicAdd(&P.tails[3], lc);
        __syncthreads();
        for (int t = tid; t < lc; t += 256) P.r1list[sm.comp.gbase + t] = sm.comp.buf[t];
    }
    grid.sync();

    // ---------------- P4: wplace (w edges with bitsR1|bitsR2 row) ----------------
    {
        const int4* wc4 = (const int4*)P.w_cols;
        const float4* wv4 = (const float4*)P.w_val;
        for (int i = gtid; i < P.e4; i += T) {
            int4 r = P.w_rows4[i];
            int4 c = wc4[i];
            float4 v = wv4[i];
            int rr[4] = {r.x, r.y, r.z, r.w};
            int cc[4] = {c.x, c.y, c.z, c.w};
            float vv[4] = {v.x, v.y, v.z, v.w};
            unsigned fl[4];
#pragma unroll
            for (int j = 0; j < 4; ++j)
                fl[j] = ((P.bitsR1[rr[j] >> 5] | P.bitsR2[rr[j] >> 5]) >> (rr[j] & 31)) & 1u;
            int pos[4];
#pragma unroll
            for (int j = 0; j < 4; ++j)
                pos[j] = fl[j] ? atomicAdd(&P.w_cnt[rr[j]], 1) : WDEG;
#pragma unroll
            for (int j = 0; j < 4; ++j)
                if (pos[j] < WDEG)
                    P.w_pairsD[(size_t)rr[j] * WDEG + pos[j]] =
                        make_int2(cc[j], __float_as_int(vv[j]));
        }
    }
    grid.sync();

    // ------- P5: gather t1_raw[r] = sum_w v * x[col]  (W1 folded out; no gemm1) -------
    {
        int r1c = P.tails[3];
        int total = r1c * 32;        // 8 float4-lanes x B=4 per row
        for (int idx = gtid; idx < total; idx += T) {
            int row = P.r1list[idx >> 5];
            int rem = idx & 31;
            int c4 = rem & 7;
            int b = rem >> 3;
            int L = P.w_cnt[row]; if (L > WDEG) L = WDEG;
            const int2* pr = P.w_pairsD + (size_t)row * WDEG;
            const float4* sb = (const float4*)P.x + (size_t)b * N * 8 + c4;  // x[b][.][c4*4]
            float4 acc = make_float4(0.f, 0.f, 0.f, 0.f);
            int i = 0;
            int L4 = L & ~3;
            for (; i < L4; i += 4) {
                int2 p0 = pr[i + 0];
                int2 p1 = pr[i + 1];
                int2 p2 = pr[i + 2];
                int2 p3 = pr[i + 3];
                float4 s0 = sb[(size_t)p0.x * 8];
                float4 s1 = sb[(size_t)p1.x * 8];
                float4 s2 = sb[(size_t)p2.x * 8];
                float4 s3 = sb[(size_t)p3.x * 8];
                float v0 = __int_as_float(p0.y), v1 = __int_as_float(p1.y);
                float v2 = __int_as_float(p2.y), v3 = __int_as_float(p3.y);
                acc.x += v0 * s0.x + v1 * s1.x + v2 * s2.x + v3 * s3.x;
                acc.y += v0 * s0.y + v1 * s1.y + v2 * s2.y + v3 * s3.y;
                acc.z += v0 * s0.z + v1 * s1.z + v2 * s2.z + v3 * s3.z;
                acc.w += v0 * s0.w + v1 * s1.w + v2 * s2.w + v3 * s3.w;
            }
            for (; i < L; ++i) {
                int2 p = pr[i];
                float4 sv = sb[(size_t)p.x * 8];
                float v = __int_as_float(p.y);
                acc.x += v * sv.x; acc.y += v * sv.y; acc.z += v * sv.z; acc.w += v * sv.w;
            }
            ((float4*)P.t1)[(size_t)row * 32 + b * 8 + c4] = acc;   // t1_raw[row][b][32]
        }
    }
    grid.sync();

    // ------- P6: per n1 slot: u = wi-agg(t1_raw); x1 = lrelu(u@W1); h2 = x1@W2 -------
    {
        for (int i = tid; i < 1024; i += 256) sm.p6.W1s[i] = P.W1[i];
        for (int i = tid; i < 512; i += 256) sm.p6.W2s[i] = P.W2[i];
        __syncthreads();
        int n1c = P.tails[2]; if (n1c > N1_CAP) n1c = N1_CAP;
        int g = tid >> 5;
        int t32 = tid & 31;
        int b = t32 >> 3, c4 = t32 & 7;
        for (int base = blockIdx.x * 8; base < n1c; base += gridDim.x * 8) {
            int s = base + g;
            bool active = (s < n1c);
            int n = 0;
            if (active) {
                n = P.n1list[s];
                int L = P.wi_cnt[n]; if (L > WIDEG) L = WIDEG;
                const int2* pr = P.wi_pairsD + (size_t)s * WIDEG;
                const float4* sb = (const float4*)P.t1 + b * 8 + c4;
                float4 acc = make_float4(0.f, 0.f, 0.f, 0.f);
                int i = 0;
                int L2 = L & ~1;
                for (; i < L2; i += 2) {
                    int2 p0 = pr[i + 0];
                    int2 p1 = pr[i + 1];
                    float4 s0 = sb[(size_t)p0.x * 32];
                    float4 s1 = sb[(size_t)p1.x * 32];
                    float v0 = __int_as_float(p0.y), v1 = __int_as_float(p1.y);
                    acc.x += v0 * s0.x + v1 * s1.x;
                    acc.y += v0 * s0.y + v1 * s1.y;
                    acc.z += v0 * s0.z + v1 * s1.z;
                    acc.w += v0 * s0.w + v1 * s1.w;
                }
                if (i < L) {
                    int2 p = pr[i];
                    float4 sv = sb[(size_t)p.x * 32];
                    float v = __int_as_float(p.y);
                    acc.x += v * sv.x; acc.y += v * sv.y; acc.z += v * sv.z; acc.w += v * sv.w;
                }
                float* up = &sm.p6.uls[g][b * 32 + c4 * 4];
                up[0] = acc.x; up[1] = acc.y; up[2] = acc.z; up[3] = acc.w;
            }
            __syncthreads();
            if (active) {
                // x1[b][c] = lrelu(sum_k u[b][k] * W1[k][c]), c = c4*4..c4*4+3
                const float* urow = &sm.p6.uls[g][b * 32];
                float o0 = 0.f, o1 = 0.f, o2 = 0.f, o3 = 0.f;
#pragma unroll
                for (int k = 0; k < 32; ++k) {
                    float uk = urow[k];
                    const float* wr = &sm.p6.W1s[k * 32 + c4 * 4];
                    o0 += uk * wr[0]; o1 += uk * wr[1]; o2 += uk * wr[2]; o3 += uk * wr[3];
                }
                float* xp = &sm.p6.x1ls[g][b * 32 + c4 * 4];
                xp[0] = o0 > 0.f ? o0 : NEG_SLOPE * o0;
                xp[1] = o1 > 0.f ? o1 : NEG_SLOPE * o1;
                xp[2] = o2 > 0.f ? o2 : NEG_SLOPE * o2;
                xp[3] = o3 > 0.f ? o3 : NEG_SLOPE * o3;
            }
            __syncthreads();
            if (active) {
#pragma unroll
                for (int half = 0; half < 2; ++half) {
                    int o = t32 + half * 32;
                    int bb = o >> 4, cc = o & 15;
                    const float* xp = &sm.p6.x1ls[g][bb * 32];
                    float acc = 0.f;
#pragma unroll
                    for (int k = 0; k < 32; ++k) acc += xp[k] * sm.p6.W2s[k * 16 + cc];
                    P.h2[(size_t)n * 64 + o] = acc;
                }
            }
            __syncthreads();
        }
    }
    grid.sync();

    // ---------------- P7+P8: t2 gather + x2 + heads (block 0 only) ----------------
    if (blockIdx.x != 0) return;
    {
        int r2c = P.tails[1]; if (r2c > R2_CAP) r2c = R2_CAP;
        for (int idx = tid; idx < r2c * 16; idx += 256) {
            int row = P.r2list[idx >> 4];
            int rem = idx & 15;
            int c4 = rem & 3;
            int b = rem >> 2;
            int L = P.w_cnt[row]; if (L > WDEG) L = WDEG;
            const int2* pr = P.w_pairsD + (size_t)row * WDEG;
            const float4* sb = (const float4*)P.h2 + b * 4 + c4;
            float4 acc = make_float4(0.f, 0.f, 0.f, 0.f);
            for (int i = 0; i < L; ++i) {
                int2 p = pr[i];
                float4 sv = sb[(size_t)p.x * 16];
                float v = __int_as_float(p.y);
                acc.x += v * sv.x; acc.y += v * sv.y; acc.z += v * sv.z; acc.w += v * sv.w;
            }
            ((float4*)P.t1)[(size_t)row * 16 + b * 4 + c4] = acc;   // t2 aliases t1
        }
    }
    __syncthreads();
    {
        int cnt = P.tails[0]; if (cnt > X2_CAP) cnt = X2_CAP;
        int g2 = tid >> 6, l = tid & 63;
        int b = l >> 4, c = l & 15;
        float a0 = 0.f, a1 = 0.f;
        for (int i = g2; i < cnt; i += 4) {
            int2 rec = P.x2list[i];
            int col = rec.x >> 1;
            float coef = __int_as_float(rec.y) * P.diag2[col];
            float v = P.t1[(size_t)col * 64 + b * 16 + c] * coef;
            if (rec.x & 1) a1 += v; else a0 += v;
        }
        sm.p8.red0[g2][l] = a0; sm.p8.red1[g2][l] = a1;
        __syncthreads();
        if (tid < 64) {
            float s0 = 0.f, s1 = 0.f;
#pragma unroll
            for (int gg = 0; gg < 4; ++gg) { s0 += sm.p8.red0[gg][tid]; s1 += sm.p8.red1[gg][tid]; }
            sm.p8.xs[0][tid] = s0; sm.p8.xs[1][tid] = s1;
        }
        __syncthreads();
        if (tid < 8) {
            int bb = tid >> 1, which = tid & 1;
            const float* w = which ? P.rw2 : P.rw1;
            float acc = which ? P.rb2[0] : P.rb1[0];
            for (int k = 0; k < 16; ++k) {
                float xv = sm.p8.xs[which][bb * 16 + k];
                xv = xv > 0.f ? xv : NEG_SLOPE * xv;
                acc += xv * w[k];
            }
            P.out[bb * 2 + which] = acc;
        }
    }
}

extern "C" void kernel_launch(void* const* d_in, const int* in_sizes, int n_in,
                              void* d_out, int out_size, void* d_ws, size_t ws_size,
                              hipStream_t stream) {
    KParams P;
    P.w_rows4  = (const int4*)d_in[0];
    P.w_cols   = ((const int*)d_in[0]) + E;
    P.w_val    = (const float*)d_in[1];
    P.wi_rows4 = (const int4*)d_in[2];
    P.wi_cols  = ((const int*)d_in[2]) + E;
    P.wi_val   = (const float*)d_in[3];
    P.x        = (const float*)d_in[4];
    P.W1       = (const float*)d_in[5];
    P.diag1    = (const float*)d_in[6];
    P.W2       = (const float*)d_in[7];
    P.diag2    = (const float*)d_in[8];
    P.rw1      = (const float*)d_in[9];
    P.rb1      = (const float*)d_in[10];
    P.rw2      = (const float*)d_in[11];
    P.rb2      = (const float*)d_in[12];
    P.out      = (float*)d_out;

    // ---------------- workspace layout ----------------
    float* t1 = (float*)d_ws;                    // [R][B][32] (51.2 MB); t2 aliases
    float* h2 = t1 + (size_t)B * R * 32;         // [N][B][16] (12.8 MB)
    int* ip = (int*)(h2 + (size_t)B * N * 16);
    // zeroed block (contiguous, ZWORDS words):
    P.w_cnt  = ip; ip += R;
    P.wi_cnt = ip; ip += N;
    P.bitsR1 = (unsigned*)ip; ip += RBW;
    P.bitsR2 = (unsigned*)ip; ip += RBW;
    P.bitsN1 = (unsigned*)ip; ip += NBW;
    P.tails  = ip; ip += 8;
    // un-zeroed:
    P.n1slot = ip; ip += N;
    P.n1list = ip; ip += N;
    P.r1list = ip; ip += R;
    P.r2list = ip; ip += R2_CAP;
    P.x2list = (int2*)ip; ip += 2 * X2_CAP;
    P.w_pairsD  = (int2*)ip; ip += 2 * (size_t)R * WDEG;          // 51.2 MB
    P.wi_pairsD = (int2*)ip; ip += 2 * (size_t)N1_CAP * WIDEG;    // 3.1 MB
    P.t1 = t1;
    P.h2 = h2;
    P.e4 = E / 4;

    static int gridsz = 0;
    if (gridsz == 0) {
        int dev = 0;
        (void)hipGetDevice(&dev);
        hipDeviceProp_t prop;
        (void)hipGetDeviceProperties(&prop, dev);
        int maxb = 0;
        (void)hipOccupancyMaxActiveBlocksPerMultiprocessor(&maxb, fused, 256, 0);
        if (maxb < 1) maxb = 1;
        long g = (long)prop.multiProcessorCount * maxb;
        if (g > 2048) g = 2048;
        if (g < 1) g = 1;
        gridsz = (int)g;
    }

    void* args[] = { &P };
    (void)hipLaunchCooperativeKernel(fused, dim3(gridsz), dim3(256), args, 0, stream);
}

// Round 4
// 452.835 us; speedup vs baseline: 1.5335x; 1.5335x over previous
//
#include <hip/hip_runtime.h>

#define NEG_SLOPE 0.2f

static const int B = 4, N = 50000, R = 100000, E = 1600000;
static const int X2_CAP = 4096;     // x2 edge list capacity (expected ~64-128)
static const int R2_CAP = 4096;     // distinct t2 rows (expected ~64)
static const int N1_CAP = 4096;     // n1 nodes (expected ~1-2k)
static const int WDEG  = 64;        // w-CSR slab per R-row (mean deg 16, P(>64)~1e-24)
static const int WIDEG = 96;        // wi-CSR slab per node (mean deg 32, P(>96)~1e-19)
static const int RBW = 3200;        // bit-words for R rows
static const int NBW = 1600;        // bit-words for N nodes
static const int ZWORDS = R + N + RBW + NBW + 8;   // w_cnt, wi_cnt, bitsR2d, bitsN1, tails

// tails: [0]=x2tail [1]=r2tail [2]=n1tail

// ---- buildK: ONE pass over both edge lists. Unconditional CSR slab build ----
// blocks cover 2*e4 int4-groups: [0,e4) = w edges, [e4,2*e4) = wi edges (+ markA).
__global__ void buildK(const int4* __restrict__ w_rows4, const int4* __restrict__ w_cols4,
                       const float4* __restrict__ w_val4,
                       const int4* __restrict__ wi_rows4, const int4* __restrict__ wi_cols4,
                       const float4* __restrict__ wi_val4,
                       int* __restrict__ w_cnt, int2* __restrict__ w_pairsD,
                       int* __restrict__ wi_cnt, int2* __restrict__ wi_pairsD,
                       unsigned* __restrict__ bitsR2d, int* __restrict__ r2list,
                       int2* __restrict__ x2list, int* __restrict__ tails, int e4) {
    int i = blockIdx.x * blockDim.x + threadIdx.x;
    if (i < e4) {
        // ---- w edge group: scatter into w-CSR slabs ----
        int4 r = w_rows4[i];
        int4 c = w_cols4[i];
        float4 v = w_val4[i];
        int rr[4] = {r.x, r.y, r.z, r.w};
        int cc[4] = {c.x, c.y, c.z, c.w};
        float vv[4] = {v.x, v.y, v.z, v.w};
        int pos[4];
#pragma unroll
        for (int j = 0; j < 4; ++j) pos[j] = atomicAdd(&w_cnt[rr[j]], 1);
#pragma unroll
        for (int j = 0; j < 4; ++j)
            if (pos[j] < WDEG)
                w_pairsD[(size_t)rr[j] * WDEG + pos[j]] =
                    make_int2(cc[j], __float_as_int(vv[j]));
    } else if (i < 2 * e4) {
        // ---- wi edge group: scatter into wi-CSR slabs + markA ----
        int k = i - e4;
        int4 r = wi_rows4[k];
        int4 c = wi_cols4[k];
        float4 v = wi_val4[k];
        int rr[4] = {r.x, r.y, r.z, r.w};
        int cc[4] = {c.x, c.y, c.z, c.w};
        float vv[4] = {v.x, v.y, v.z, v.w};
        int pos[4];
#pragma unroll
        for (int j = 0; j < 4; ++j) pos[j] = atomicAdd(&wi_cnt[rr[j]], 1);
#pragma unroll
        for (int j = 0; j < 4; ++j)
            if (pos[j] < WIDEG)
                wi_pairsD[(size_t)rr[j] * WIDEG + pos[j]] =
                    make_int2(cc[j], __float_as_int(vv[j]));
#pragma unroll
        for (int j = 0; j < 4; ++j) {
            if (rr[j] >= N - 2) {
                int col = cc[j];
                unsigned old = atomicOr(&bitsR2d[col >> 5], 1u << (col & 31));
                if (!((old >> (col & 31)) & 1u)) {
                    int p = atomicAdd(&tails[1], 1);
                    if (p < R2_CAP) r2list[p] = col;
                }
                int q = atomicAdd(&tails[0], 1);
                if (q < X2_CAP)
                    x2list[q] = make_int2(col * 2 + (rr[j] - (N - 2)),
                                          __float_as_int(vv[j]));
            }
        }
    }
}

// ---- n1build: walk r2 rows' w-slabs (~1k edges) -> distinct cols = n1list ----
__global__ void n1build(const int* __restrict__ r2list,
                        const int* __restrict__ w_cnt, const int2* __restrict__ w_pairsD,
                        unsigned* __restrict__ bitsN1, int* __restrict__ n1list,
                        int* __restrict__ tails) {
    int r2c = tails[1]; if (r2c > R2_CAP) r2c = R2_CAP;
    int total = r2c * WDEG;
    for (int item = threadIdx.x; item < total; item += blockDim.x) {
        int ri = item >> 6;             // WDEG = 64
        int e  = item & 63;
        int row = r2list[ri];
        int L = w_cnt[row]; if (L > WDEG) L = WDEG;
        if (e < L) {
            int c = w_pairsD[(size_t)row * WDEG + e].x;
            unsigned old = atomicOr(&bitsN1[c >> 5], 1u << (c & 31));
            if (!((old >> (c & 31)) & 1u)) {
                int p = atomicAdd(&tails[2], 1);
                if (p < N1_CAP) n1list[p] = c;
            }
        }
    }
}

// ---- x1mlp: per n1 node, two-hop gather u = (wi.diag1).w.x ; h2 = lrelu(u@W1)@W2 ----
// One block per slot; 8 wi-edge processors x 32 threads (b = t32>>3, c4 = t32&7).
__global__ void __launch_bounds__(256) x1mlp(
        const float* __restrict__ x, const float* __restrict__ diag1,
        const float* __restrict__ W1, const float* __restrict__ W2,
        const int* __restrict__ n1list, const int* __restrict__ tails,
        const int* __restrict__ wi_cnt, const int2* __restrict__ wi_pairsD,
        const int* __restrict__ w_cnt, const int2* __restrict__ w_pairsD,
        float* __restrict__ h2) {
    __shared__ float W1s[1024], W2s[512];
    __shared__ float uls[8][128];
    __shared__ float ufin[128], x1ls[128];
    for (int i = threadIdx.x; i < 1024; i += 256) W1s[i] = W1[i];
    for (int i = threadIdx.x; i < 512; i += 256) W2s[i] = W2[i];
    int n1c = tails[2]; if (n1c > N1_CAP) n1c = N1_CAP;
    int g = threadIdx.x >> 5, t32 = threadIdx.x & 31;
    int b = t32 >> 3, c4 = t32 & 7;
    const float4* xb = (const float4*)x + (size_t)b * N * 8 + c4;
    for (int s = blockIdx.x; s < n1c; s += gridDim.x) {
        int n = n1list[s];
        int L = wi_cnt[n]; if (L > WIDEG) L = WIDEG;
        const int2* wip = wi_pairsD + (size_t)n * WIDEG;
        float4 acc = make_float4(0.f, 0.f, 0.f, 0.f);
        for (int e = g; e < L; e += 8) {
            int2 pe = wip[e];
            int r = pe.x;
            float coef = __int_as_float(pe.y) * diag1[r];
            int Lw = w_cnt[r]; if (Lw > WDEG) Lw = WDEG;
            const int2* pr = w_pairsD + (size_t)r * WDEG;
            float4 t = make_float4(0.f, 0.f, 0.f, 0.f);
            int i = 0;
            int L4 = Lw & ~3;
            for (; i < L4; i += 4) {
                int2 p0 = pr[i + 0];
                int2 p1 = pr[i + 1];
                int2 p2 = pr[i + 2];
                int2 p3 = pr[i + 3];
                float4 s0 = xb[(size_t)p0.x * 8];
                float4 s1 = xb[(size_t)p1.x * 8];
                float4 s2 = xb[(size_t)p2.x * 8];
                float4 s3 = xb[(size_t)p3.x * 8];
                float v0 = __int_as_float(p0.y), v1 = __int_as_float(p1.y);
                float v2 = __int_as_float(p2.y), v3 = __int_as_float(p3.y);
                t.x += v0 * s0.x + v1 * s1.x + v2 * s2.x + v3 * s3.x;
                t.y += v0 * s0.y + v1 * s1.y + v2 * s2.y + v3 * s3.y;
                t.z += v0 * s0.z + v1 * s1.z + v2 * s2.z + v3 * s3.z;
                t.w += v0 * s0.w + v1 * s1.w + v2 * s2.w + v3 * s3.w;
            }
            for (; i < Lw; ++i) {
                int2 p = pr[i];
                float4 sv = xb[(size_t)p.x * 8];
                float v = __int_as_float(p.y);
                t.x += v * sv.x; t.y += v * sv.y; t.z += v * sv.z; t.w += v * sv.w;
            }
            acc.x += coef * t.x; acc.y += coef * t.y;
            acc.z += coef * t.z; acc.w += coef * t.w;
        }
        float* up = &uls[g][b * 32 + c4 * 4];
        up[0] = acc.x; up[1] = acc.y; up[2] = acc.z; up[3] = acc.w;
        __syncthreads();
        if (threadIdx.x < 128) {
            float sum = 0.f;
#pragma unroll
            for (int gg = 0; gg < 8; ++gg) sum += uls[gg][threadIdx.x];
            ufin[threadIdx.x] = sum;
        }
        __syncthreads();
        if (threadIdx.x < 128) {
            int bb = threadIdx.x >> 5, c = threadIdx.x & 31;
            const float* ur = &ufin[bb * 32];
            float o = 0.f;
#pragma unroll
            for (int k = 0; k < 32; ++k) o += ur[k] * W1s[k * 32 + c];
            x1ls[threadIdx.x] = o > 0.f ? o : NEG_SLOPE * o;
        }
        __syncthreads();
        if (threadIdx.x < 64) {
            int bb = threadIdx.x >> 4, c = threadIdx.x & 15;
            const float* xr = &x1ls[bb * 32];
            float o = 0.f;
#pragma unroll
            for (int k = 0; k < 32; ++k) o += xr[k] * W2s[k * 16 + c];
            h2[(size_t)n * 64 + bb * 16 + c] = o;
        }
        __syncthreads();
    }
}

// ---- t2 gather + x2 accumulation + heads, ONE block of 1024 threads ----
__global__ void t2x2heads(const float* __restrict__ h2,
                          const int* __restrict__ w_cnt, const int2* __restrict__ w_pairsD,
                          const int* __restrict__ r2list, const int* __restrict__ tails,
                          float* __restrict__ t2,
                          const int2* __restrict__ x2list,
                          const float* __restrict__ diag2,
                          const float* __restrict__ rw1, const float* __restrict__ rb1,
                          const float* __restrict__ rw2, const float* __restrict__ rb2,
                          float* __restrict__ out) {
    // phase 1: t2 gather over r2 rows, 16 float4-lanes per row
    int r2c = tails[1]; if (r2c > R2_CAP) r2c = R2_CAP;
    for (int idx = threadIdx.x; idx < r2c * 16; idx += blockDim.x) {
        int row = r2list[idx >> 4];
        int rem = idx & 15;
        int c4 = rem & 3;
        int b = rem >> 2;
        int L = w_cnt[row]; if (L > WDEG) L = WDEG;
        const int2* pr = w_pairsD + (size_t)row * WDEG;
        const float4* sb = (const float4*)h2 + b * 4 + c4;
        float4 acc = make_float4(0.f, 0.f, 0.f, 0.f);
        for (int i = 0; i < L; ++i) {
            int2 p = pr[i];
            float4 sv = sb[(size_t)p.x * 16];
            float v = __int_as_float(p.y);
            acc.x += v * sv.x; acc.y += v * sv.y; acc.z += v * sv.z; acc.w += v * sv.w;
        }
        ((float4*)t2)[(size_t)row * 16 + b * 4 + c4] = acc;
    }
    __syncthreads();

    // phase 2: x2 accumulation, edge-parallel across 16 groups of 64 lanes
    int cnt = tails[0]; if (cnt > X2_CAP) cnt = X2_CAP;
    int g = threadIdx.x >> 6, l = threadIdx.x & 63;
    int b = l >> 4, c = l & 15;
    float a0 = 0.f, a1 = 0.f;
    for (int i = g; i < cnt; i += 16) {
        int2 rec = x2list[i];
        int col = rec.x >> 1;
        float coef = __int_as_float(rec.y) * diag2[col];
        float v = t2[(size_t)col * 64 + b * 16 + c] * coef;
        if (rec.x & 1) a1 += v; else a0 += v;
    }
    __shared__ float red0[16][64], red1[16][64], xs[2][64];
    red0[g][l] = a0; red1[g][l] = a1;
    __syncthreads();
    if (threadIdx.x < 64) {
        float s0 = 0.f, s1 = 0.f;
#pragma unroll
        for (int gg = 0; gg < 16; ++gg) { s0 += red0[gg][threadIdx.x]; s1 += red1[gg][threadIdx.x]; }
        xs[0][threadIdx.x] = s0; xs[1][threadIdx.x] = s1;
    }
    __syncthreads();
    if (threadIdx.x < 8) {
        int bb = threadIdx.x >> 1, which = threadIdx.x & 1;
        const float* w = which ? rw2 : rw1;
        float acc = which ? rb2[0] : rb1[0];
        for (int k = 0; k < 16; ++k) {
            float xv = xs[which][bb * 16 + k];
            xv = xv > 0.f ? xv : NEG_SLOPE * xv;
            acc += xv * w[k];
        }
        out[bb * 2 + which] = acc;
    }
}

extern "C" void kernel_launch(void* const* d_in, const int* in_sizes, int n_in,
                              void* d_out, int out_size, void* d_ws, size_t ws_size,
                              hipStream_t stream) {
    const int*   w_rows  = (const int*)d_in[0];
    const int*   w_cols  = ((const int*)d_in[0]) + E;
    const float* w_val   = (const float*)d_in[1];
    const int*   wi_rows = (const int*)d_in[2];
    const int*   wi_cols = ((const int*)d_in[2]) + E;
    const float* wi_val  = (const float*)d_in[3];
    const float* x       = (const float*)d_in[4];
    const float* W1      = (const float*)d_in[5];
    const float* diag1   = (const float*)d_in[6];
    const float* W2      = (const float*)d_in[7];
    const float* diag2   = (const float*)d_in[8];
    const float* rw1     = (const float*)d_in[9];
    const float* rb1     = (const float*)d_in[10];
    const float* rw2     = (const float*)d_in[11];
    const float* rb2     = (const float*)d_in[12];
    float* out = (float*)d_out;

    // ---------------- workspace layout (~129 MB) ----------------
    float* h2 = (float*)d_ws;                    // [N][B][16] (12.8 MB)
    float* t2 = h2 + (size_t)B * N * 16;         // [R][B][16] (25.6 MB, sparse use)
    int* ip = (int*)(t2 + (size_t)B * R * 16);
    // zeroed block (contiguous, ZWORDS words):
    int* w_cnt  = ip; ip += R;
    int* wi_cnt = ip; ip += N;
    unsigned* bitsR2d = (unsigned*)ip; ip += RBW;
    unsigned* bitsN1  = (unsigned*)ip; ip += NBW;
    int* tails = ip; ip += 8;
    // un-zeroed:
    int* n1list = ip; ip += N1_CAP;
    int* r2list = ip; ip += R2_CAP;
    int2* x2list = (int2*)ip; ip += 2 * X2_CAP;
    int2* w_pairsD  = (int2*)ip; ip += 2 * (size_t)R * WDEG;      // 51.2 MB
    int2* wi_pairsD = (int2*)ip; ip += 2 * (size_t)N * WIDEG;     // 38.4 MB

    const int e4 = E / 4;

    (void)hipMemsetAsync(w_cnt, 0, (size_t)ZWORDS * sizeof(int), stream);

    // 1) single pass: both CSR slab builds + markA
    buildK<<<(2 * e4 + 255) / 256, 256, 0, stream>>>(
        (const int4*)w_rows, (const int4*)w_cols, (const float4*)w_val,
        (const int4*)wi_rows, (const int4*)wi_cols, (const float4*)wi_val,
        w_cnt, w_pairsD, wi_cnt, wi_pairsD,
        bitsR2d, r2list, x2list, tails, e4);

    // 2) n1 discovery from r2 rows' slabs (~1k edges)
    n1build<<<1, 256, 0, stream>>>(r2list, w_cnt, w_pairsD, bitsN1, n1list, tails);

    // 3) two-hop gather + MLP for n1 nodes
    x1mlp<<<1024, 256, 0, stream>>>(x, diag1, W1, W2, n1list, tails,
                                    wi_cnt, wi_pairsD, w_cnt, w_pairsD, h2);

    // 4) t2 gather + x2 + heads
    t2x2heads<<<1, 1024, 0, stream>>>(h2, w_cnt, w_pairsD, r2list, tails,
                                      t2, x2list, diag2, rw1, rb1, rw2, rb2, out);
}

// Round 5
// 439.164 us; speedup vs baseline: 1.5813x; 1.0311x over previous
//
#include <hip/hip_runtime.h>

#define NEG_SLOPE 0.2f

static const int B = 4, N = 50000, R = 100000, E = 1600000;
static const int X2_CAP = 4096;     // x2 edge records (expected ~64)
static const int R2_CAP = 4096;     // r2 rows (expected ~64)
static const int N1_CAP = 4096;     // n1 nodes (expected ~1k)
static const int RS_CAP = 49152;    // row slots, r2 + r1 (expected ~28k)
static const int WDEG  = 64;        // w-CSR slab per slot (mean deg 16)
static const int WIDEG = 96;        // wi-CSR slab per n1 slot (mean deg 32)
static const int RBW = 3200;        // bit-words for R rows
static const int NBW = 1600;        // bit-words for N nodes
static const int ZWORDS = RS_CAP + N1_CAP + RBW + NBW + 8;
// tails: [0]=x2tail [1]=unused [2]=n1tail [3]=slotTail [4]=r2c snapshot

// ---- scanA: wi edges with row>=N-2 -> x2list + r2 rows get slots [0,r2c) ----
__global__ void scanA(const int4* __restrict__ wi_rows4, const int4* __restrict__ wi_cols4,
                      const float4* __restrict__ wi_val4,
                      unsigned* __restrict__ bitsRS, int* __restrict__ rslot,
                      int* __restrict__ slotrow, int2* __restrict__ x2list,
                      int* __restrict__ tails, int e4) {
    int i = blockIdx.x * blockDim.x + threadIdx.x;
    if (i >= e4) return;
    int4 r = wi_rows4[i];
    int rr[4] = {r.x, r.y, r.z, r.w};
    bool any = false;
#pragma unroll
    for (int j = 0; j < 4; ++j) any = any || (rr[j] >= N - 2);
    if (!any) return;
    int4 c = wi_cols4[i];
    float4 v = wi_val4[i];
    int cc[4] = {c.x, c.y, c.z, c.w};
    float vv[4] = {v.x, v.y, v.z, v.w};
#pragma unroll
    for (int j = 0; j < 4; ++j) {
        if (rr[j] >= N - 2) {
            int col = cc[j];
            unsigned m = 1u << (col & 31);
            unsigned old = atomicOr(&bitsRS[col >> 5], m);
            if (!(old & m)) {
                int s = atomicAdd(&tails[3], 1);
                if (s < RS_CAP) { rslot[col] = s; slotrow[s] = col; }
            }
            int q = atomicAdd(&tails[0], 1);
            if (q < X2_CAP)
                x2list[q] = make_int2(col * 2 + (rr[j] - (N - 2)),
                                      __float_as_int(vv[j]));
        }
    }
}

// ---- scanB: w edges with row in r2 (bitsRS) -> n1 set (bitsN1 + n1slot) ----
__global__ void scanB(const int4* __restrict__ w_rows4, const int4* __restrict__ w_cols4,
                      const unsigned* __restrict__ bitsRS, unsigned* __restrict__ bitsN1,
                      int* __restrict__ n1slot, int* __restrict__ tails, int e4) {
    if (blockIdx.x == 0 && threadIdx.x == 0) tails[4] = tails[3];  // snapshot r2c
    int i = blockIdx.x * blockDim.x + threadIdx.x;
    if (i >= e4) return;
    int4 r = w_rows4[i];
    int rr[4] = {r.x, r.y, r.z, r.w};
    unsigned fb[4];
#pragma unroll
    for (int j = 0; j < 4; ++j) fb[j] = (bitsRS[rr[j] >> 5] >> (rr[j] & 31)) & 1u;
    if (!(fb[0] | fb[1] | fb[2] | fb[3])) return;
    int4 c = w_cols4[i];
    int cc[4] = {c.x, c.y, c.z, c.w};
#pragma unroll
    for (int j = 0; j < 4; ++j) {
        if (fb[j]) {
            int n = cc[j];
            unsigned m = 1u << (n & 31);
            unsigned old = atomicOr(&bitsN1[n >> 5], m);
            if (!(old & m)) {
                int p = atomicAdd(&tails[2], 1);
                if (p < N1_CAP) n1slot[n] = p;
            }
        }
    }
}

// ---- scanC: wi edges with node-row in n1 -> wi-place (compact) + r1 slots ----
__global__ void scanC(const int4* __restrict__ wi_rows4, const int4* __restrict__ wi_cols4,
                      const float4* __restrict__ wi_val4, const float* __restrict__ diag1,
                      const unsigned* __restrict__ bitsN1, const int* __restrict__ n1slot,
                      unsigned* __restrict__ bitsRS, int* __restrict__ rslot,
                      int* __restrict__ slotrow, int* __restrict__ wi_cntC,
                      int2* __restrict__ wi_pairs, int* __restrict__ tails, int e4) {
    int i = blockIdx.x * blockDim.x + threadIdx.x;
    if (i >= e4) return;
    int4 r = wi_rows4[i];
    int rr[4] = {r.x, r.y, r.z, r.w};
    unsigned fb[4];
#pragma unroll
    for (int j = 0; j < 4; ++j) fb[j] = (bitsN1[rr[j] >> 5] >> (rr[j] & 31)) & 1u;
    if (!(fb[0] | fb[1] | fb[2] | fb[3])) return;
    int4 c = wi_cols4[i];
    float4 v = wi_val4[i];
    int cc[4] = {c.x, c.y, c.z, c.w};
    float vv[4] = {v.x, v.y, v.z, v.w};
#pragma unroll
    for (int j = 0; j < 4; ++j) {
        if (fb[j]) {
            int col = cc[j];
            float cf = vv[j] * diag1[col];
            int slot = n1slot[rr[j]];
            if (slot >= 0 && slot < N1_CAP) {
                int pos = atomicAdd(&wi_cntC[slot], 1);
                if (pos < WIDEG)
                    wi_pairs[(size_t)slot * WIDEG + pos] =
                        make_int2(col, __float_as_int(cf));
            }
            unsigned m = 1u << (col & 31);
            unsigned old = atomicOr(&bitsRS[col >> 5], m);
            if (!(old & m)) {
                int s = atomicAdd(&tails[3], 1);
                if (s < RS_CAP) { rslot[col] = s; slotrow[s] = col; }
            }
        }
    }
}

// ---- scanD: w edges with slotted row (r1|r2) -> compact w-slab place ----
__global__ void scanD(const int4* __restrict__ w_rows4, const int4* __restrict__ w_cols4,
                      const float4* __restrict__ w_val4,
                      const unsigned* __restrict__ bitsRS, const int* __restrict__ rslot,
                      int* __restrict__ w_cntC, int2* __restrict__ w_pairs, int e4) {
    int i = blockIdx.x * blockDim.x + threadIdx.x;
    if (i >= e4) return;
    int4 r = w_rows4[i];
    int rr[4] = {r.x, r.y, r.z, r.w};
    unsigned fb[4];
#pragma unroll
    for (int j = 0; j < 4; ++j) fb[j] = (bitsRS[rr[j] >> 5] >> (rr[j] & 31)) & 1u;
    if (!(fb[0] | fb[1] | fb[2] | fb[3])) return;
    int4 c = w_cols4[i];
    float4 v = w_val4[i];
    int cc[4] = {c.x, c.y, c.z, c.w};
    float vv[4] = {v.x, v.y, v.z, v.w};
    int s[4];
#pragma unroll
    for (int j = 0; j < 4; ++j) s[j] = fb[j] ? rslot[rr[j]] : RS_CAP;
#pragma unroll
    for (int j = 0; j < 4; ++j) {
        if (fb[j] && s[j] < RS_CAP) {
            int pos = atomicAdd(&w_cntC[s[j]], 1);
            if (pos < WDEG)
                w_pairs[(size_t)s[j] * WDEG + pos] =
                    make_int2(cc[j], __float_as_int(vv[j]));
        }
    }
}

// ---- gather_t1: per slot, t1C[s] = sum_w v * x[col]  (32 threads/slot) ----
__global__ void gather_t1(const float* __restrict__ x, float* __restrict__ t1C,
                          const int* __restrict__ w_cntC, const int2* __restrict__ w_pairs,
                          const int* __restrict__ tails) {
    int tot = tails[3]; if (tot > RS_CAP) tot = RS_CAP;
    int total = tot * 32;
    int gstride = gridDim.x * blockDim.x;
    for (int idx = blockIdx.x * blockDim.x + threadIdx.x; idx < total; idx += gstride) {
        int s = idx >> 5;
        int rem = idx & 31;
        int c4 = rem & 7;
        int b = rem >> 3;
        int L = w_cntC[s]; if (L > WDEG) L = WDEG;
        const int2* pr = w_pairs + (size_t)s * WDEG;
        const float4* sb = (const float4*)x + (size_t)b * N * 8 + c4;
        float4 acc = make_float4(0.f, 0.f, 0.f, 0.f);
        int i = 0;
        int L4 = L & ~3;
        for (; i < L4; i += 4) {
            int2 p0 = pr[i + 0];
            int2 p1 = pr[i + 1];
            int2 p2 = pr[i + 2];
            int2 p3 = pr[i + 3];
            float4 s0 = sb[(size_t)p0.x * 8];
            float4 s1 = sb[(size_t)p1.x * 8];
            float4 s2 = sb[(size_t)p2.x * 8];
            float4 s3 = sb[(size_t)p3.x * 8];
            float v0 = __int_as_float(p0.y), v1 = __int_as_float(p1.y);
            float v2 = __int_as_float(p2.y), v3 = __int_as_float(p3.y);
            acc.x += v0 * s0.x + v1 * s1.x + v2 * s2.x + v3 * s3.x;
            acc.y += v0 * s0.y + v1 * s1.y + v2 * s2.y + v3 * s3.y;
            acc.z += v0 * s0.z + v1 * s1.z + v2 * s2.z + v3 * s3.z;
            acc.w += v0 * s0.w + v1 * s1.w + v2 * s2.w + v3 * s3.w;
        }
        for (; i < L; ++i) {
            int2 p = pr[i];
            float4 sv = sb[(size_t)p.x * 8];
            float v = __int_as_float(p.y);
            acc.x += v * sv.x; acc.y += v * sv.y; acc.z += v * sv.z; acc.w += v * sv.w;
        }
        ((float4*)t1C)[(size_t)s * 32 + b * 8 + c4] = acc;
    }
}

// ---- x1mlp: per n1 slot, u = wi-agg(t1C); h2C = lrelu(u@W1)@W2 ----
__global__ void __launch_bounds__(256) x1mlp(
        const float* __restrict__ diag1_unused, const float* __restrict__ W1,
        const float* __restrict__ W2, const int* __restrict__ tails,
        const int* __restrict__ wi_cntC, const int2* __restrict__ wi_pairs,
        const int* __restrict__ rslot, const float* __restrict__ t1C,
        float* __restrict__ h2C) {
    __shared__ float W1s[1024], W2s[512];
    __shared__ float uls[8][128];
    __shared__ float ufin[128], x1ls[128];
    for (int i = threadIdx.x; i < 1024; i += 256) W1s[i] = W1[i];
    for (int i = threadIdx.x; i < 512; i += 256) W2s[i] = W2[i];
    int n1c = tails[2]; if (n1c > N1_CAP) n1c = N1_CAP;
    int g = threadIdx.x >> 5, t32 = threadIdx.x & 31;
    int b = t32 >> 3, c4 = t32 & 7;
    const float4* t1f4 = (const float4*)t1C;
    for (int s = blockIdx.x; s < n1c; s += gridDim.x) {
        int L = wi_cntC[s]; if (L > WIDEG) L = WIDEG;
        const int2* wip = wi_pairs + (size_t)s * WIDEG;
        float4 acc = make_float4(0.f, 0.f, 0.f, 0.f);
        for (int e = g; e < L; e += 8) {
            int2 pe = wip[e];
            int rs = rslot[pe.x];
            float coef = __int_as_float(pe.y);        // diag1 already folded
            if (rs < RS_CAP) {
                float4 tv = t1f4[(size_t)rs * 32 + b * 8 + c4];
                acc.x += coef * tv.x; acc.y += coef * tv.y;
                acc.z += coef * tv.z; acc.w += coef * tv.w;
            }
        }
        float* up = &uls[g][b * 32 + c4 * 4];
        up[0] = acc.x; up[1] = acc.y; up[2] = acc.z; up[3] = acc.w;
        __syncthreads();
        if (threadIdx.x < 128) {
            float sum = 0.f;
#pragma unroll
            for (int gg = 0; gg < 8; ++gg) sum += uls[gg][threadIdx.x];
            ufin[threadIdx.x] = sum;
        }
        __syncthreads();
        if (threadIdx.x < 128) {
            int bb = threadIdx.x >> 5, c = threadIdx.x & 31;
            const float* ur = &ufin[bb * 32];
            float o = 0.f;
#pragma unroll
            for (int k = 0; k < 32; ++k) o += ur[k] * W1s[k * 32 + c];
            x1ls[threadIdx.x] = o > 0.f ? o : NEG_SLOPE * o;
        }
        __syncthreads();
        if (threadIdx.x < 64) {
            int bb = threadIdx.x >> 4, c = threadIdx.x & 15;
            const float* xr = &x1ls[bb * 32];
            float o = 0.f;
#pragma unroll
            for (int k = 0; k < 32; ++k) o += xr[k] * W2s[k * 16 + c];
            h2C[(size_t)s * 64 + bb * 16 + c] = o;
        }
        __syncthreads();
    }
}

// ---- t2 gather (r2 slots) + x2 accumulation + heads, ONE block of 1024 ----
__global__ void t2x2heads(const float* __restrict__ h2C,
                          const int* __restrict__ w_cntC, const int2* __restrict__ w_pairs,
                          const int* __restrict__ n1slot, const int* __restrict__ rslot,
                          const int* __restrict__ tails, float* __restrict__ t2C,
                          const int2* __restrict__ x2list,
                          const float* __restrict__ diag2,
                          const float* __restrict__ rw1, const float* __restrict__ rb1,
                          const float* __restrict__ rw2, const float* __restrict__ rb2,
                          float* __restrict__ out) {
    // phase 1: t2 over r2 slots [0, r2c), 16 float4-lanes per slot
    int r2c = tails[4]; if (r2c > R2_CAP) r2c = R2_CAP;
    for (int idx = threadIdx.x; idx < r2c * 16; idx += blockDim.x) {
        int s = idx >> 4;
        int rem = idx & 15;
        int c4 = rem & 3;
        int b = rem >> 2;
        int L = w_cntC[s]; if (L > WDEG) L = WDEG;
        const int2* pr = w_pairs + (size_t)s * WDEG;
        const float4* sb = (const float4*)h2C + b * 4 + c4;
        float4 acc = make_float4(0.f, 0.f, 0.f, 0.f);
        for (int i = 0; i < L; ++i) {
            int2 p = pr[i];
            int hs = n1slot[p.x];               // col is n1 by construction
            float v = __int_as_float(p.y);
            if (hs >= 0 && hs < N1_CAP) {
                float4 sv = sb[(size_t)hs * 16];
                acc.x += v * sv.x; acc.y += v * sv.y; acc.z += v * sv.z; acc.w += v * sv.w;
            }
        }
        ((float4*)t2C)[(size_t)s * 16 + b * 4 + c4] = acc;
    }
    __syncthreads();

    // phase 2: x2 accumulation, edge-parallel across 16 groups of 64 lanes
    int cnt = tails[0]; if (cnt > X2_CAP) cnt = X2_CAP;
    int g = threadIdx.x >> 6, l = threadIdx.x & 63;
    int b = l >> 4, c = l & 15;
    float a0 = 0.f, a1 = 0.f;
    for (int i = g; i < cnt; i += 16) {
        int2 rec = x2list[i];
        int col = rec.x >> 1;
        int s = rslot[col];
        float coef = __int_as_float(rec.y) * diag2[col];
        float v = (s < R2_CAP) ? t2C[(size_t)s * 64 + b * 16 + c] * coef : 0.f;
        if (rec.x & 1) a1 += v; else a0 += v;
    }
    __shared__ float red0[16][64], red1[16][64], xs[2][64];
    red0[g][l] = a0; red1[g][l] = a1;
    __syncthreads();
    if (threadIdx.x < 64) {
        float s0 = 0.f, s1 = 0.f;
#pragma unroll
        for (int gg = 0; gg < 16; ++gg) { s0 += red0[gg][threadIdx.x]; s1 += red1[gg][threadIdx.x]; }
        xs[0][threadIdx.x] = s0; xs[1][threadIdx.x] = s1;
    }
    __syncthreads();
    if (threadIdx.x < 8) {
        int bb = threadIdx.x >> 1, which = threadIdx.x & 1;
        const float* w = which ? rw2 : rw1;
        float acc = which ? rb2[0] : rb1[0];
        for (int k = 0; k < 16; ++k) {
            float xv = xs[which][bb * 16 + k];
            xv = xv > 0.f ? xv : NEG_SLOPE * xv;
            acc += xv * w[k];
        }
        out[bb * 2 + which] = acc;
    }
}

extern "C" void kernel_launch(void* const* d_in, const int* in_sizes, int n_in,
                              void* d_out, int out_size, void* d_ws, size_t ws_size,
                              hipStream_t stream) {
    const int*   w_rows  = (const int*)d_in[0];
    const int*   w_cols  = ((const int*)d_in[0]) + E;
    const float* w_val   = (const float*)d_in[1];
    const int*   wi_rows = (const int*)d_in[2];
    const int*   wi_cols = ((const int*)d_in[2]) + E;
    const float* wi_val  = (const float*)d_in[3];
    const float* x       = (const float*)d_in[4];
    const float* W1      = (const float*)d_in[5];
    const float* diag1   = (const float*)d_in[6];
    const float* W2      = (const float*)d_in[7];
    const float* diag2   = (const float*)d_in[8];
    const float* rw1     = (const float*)d_in[9];
    const float* rb1     = (const float*)d_in[10];
    const float* rw2     = (const float*)d_in[11];
    const float* rb2     = (const float*)d_in[12];
    float* out = (float*)d_out;

    // ---------------- workspace layout (~56 MB) ----------------
    float* t1C = (float*)d_ws;                       // [RS_CAP][128] (25.2 MB)
    float* h2C = t1C + (size_t)RS_CAP * 128;         // [N1_CAP][64]  (1 MB)
    float* t2C = h2C + (size_t)N1_CAP * 64;          // [R2_CAP][64]  (1 MB)
    int* ip = (int*)(t2C + (size_t)R2_CAP * 64);
    // zeroed block (contiguous, ZWORDS words):
    int* w_cntC  = ip; ip += RS_CAP;
    int* wi_cntC = ip; ip += N1_CAP;
    unsigned* bitsRS = (unsigned*)ip; ip += RBW;
    unsigned* bitsN1 = (unsigned*)ip; ip += NBW;
    int* tails = ip; ip += 8;
    // un-zeroed:
    int* rslot   = ip; ip += R;
    int* slotrow = ip; ip += RS_CAP;
    int* n1slot  = ip; ip += N;
    int2* x2list = (int2*)ip; ip += 2 * X2_CAP;
    int2* w_pairs  = (int2*)ip; ip += 2 * (size_t)RS_CAP * WDEG;   // 25.2 MB
    int2* wi_pairs = (int2*)ip; ip += 2 * (size_t)N1_CAP * WIDEG;  // 3.1 MB

    const int e4 = E / 4;
    const int blk = 256;
    const int scanGrid = (e4 + blk - 1) / blk;

    (void)hipMemsetAsync(w_cntC, 0, (size_t)ZWORDS * sizeof(int), stream);

    scanA<<<scanGrid, blk, 0, stream>>>((const int4*)wi_rows, (const int4*)wi_cols,
                                        (const float4*)wi_val, bitsRS, rslot, slotrow,
                                        x2list, tails, e4);
    scanB<<<scanGrid, blk, 0, stream>>>((const int4*)w_rows, (const int4*)w_cols,
                                        bitsRS, bitsN1, n1slot, tails, e4);
    scanC<<<scanGrid, blk, 0, stream>>>((const int4*)wi_rows, (const int4*)wi_cols,
                                        (const float4*)wi_val, diag1, bitsN1, n1slot,
                                        bitsRS, rslot, slotrow, wi_cntC, wi_pairs,
                                        tails, e4);
    scanD<<<scanGrid, blk, 0, stream>>>((const int4*)w_rows, (const int4*)w_cols,
                                        (const float4*)w_val, bitsRS, rslot,
                                        w_cntC, w_pairs, e4);
    gather_t1<<<2048, blk, 0, stream>>>(x, t1C, w_cntC, w_pairs, tails);
    x1mlp<<<1024, blk, 0, stream>>>(diag1, W1, W2, tails, wi_cntC, wi_pairs,
                                    rslot, t1C, h2C);
    t2x2heads<<<1, 1024, 0, stream>>>(h2C, w_cntC, w_pairs, n1slot, rslot, tails,
                                      t2C, x2list, diag2, rw1, rb1, rw2, rb2, out);
}

// Round 6
// 272.226 us; speedup vs baseline: 2.5509x; 1.6132x over previous
//
#include <hip/hip_runtime.h>

#define NEG_SLOPE 0.2f

static const int B = 4, N = 50000, R = 100000, E = 1600000;
static const int X2_CAP = 4096;     // x2 edge records (expected ~64)
static const int R2_CAP = 4096;     // r2 rows (expected ~64)
static const int N1_CAP = 4096;     // n1 nodes (expected ~1k)
static const int RS_CAP = 49152;    // row slots, r2 + r1 (expected ~28k)
static const int WDEG  = 64;        // w-CSR slab per slot (mean deg 16)
static const int WIDEG = 96;        // wi-CSR slab per n1 slot (mean deg 32)
static const int RBW = 3200;        // bit-words for R rows
static const int NBW = 1600;        // bit-words for N nodes
static const int ZWORDS = RS_CAP + N1_CAP + RBW + NBW + 8;
// tails: [0]=x2tail [1]=unused [2]=n1tail [3]=slotTail [4]=r2c snapshot

// ---- scanA: wi edges with row>=N-2 -> x2list + r2 rows get slots [0,r2c) ----
// ~64 winners total: per-winner global atomics are negligible here.
__global__ void scanA(const int4* __restrict__ wi_rows4, const int4* __restrict__ wi_cols4,
                      const float4* __restrict__ wi_val4,
                      unsigned* __restrict__ bitsRS, int* __restrict__ rslot,
                      int* __restrict__ slotrow, int2* __restrict__ x2list,
                      int* __restrict__ tails, int e4) {
    int i = blockIdx.x * blockDim.x + threadIdx.x;
    if (i >= e4) return;
    int4 r = wi_rows4[i];
    int rr[4] = {r.x, r.y, r.z, r.w};
    bool any = false;
#pragma unroll
    for (int j = 0; j < 4; ++j) any = any || (rr[j] >= N - 2);
    if (!any) return;
    int4 c = wi_cols4[i];
    float4 v = wi_val4[i];
    int cc[4] = {c.x, c.y, c.z, c.w};
    float vv[4] = {v.x, v.y, v.z, v.w};
#pragma unroll
    for (int j = 0; j < 4; ++j) {
        if (rr[j] >= N - 2) {
            int col = cc[j];
            unsigned m = 1u << (col & 31);
            unsigned old = atomicOr(&bitsRS[col >> 5], m);
            if (!(old & m)) {
                int s = atomicAdd(&tails[3], 1);
                if (s < RS_CAP) { rslot[col] = s; slotrow[s] = col; }
            }
            int q = atomicAdd(&tails[0], 1);
            if (q < X2_CAP)
                x2list[q] = make_int2(col * 2 + (rr[j] - (N - 2)),
                                      __float_as_int(vv[j]));
        }
    }
}

// ---- scanB: w edges with row in r2 (bitsRS) -> n1 set, slot via block-agg ----
__global__ void scanB(const int4* __restrict__ w_rows4, const int4* __restrict__ w_cols4,
                      const unsigned* __restrict__ bitsRS, unsigned* __restrict__ bitsN1,
                      int* __restrict__ n1slot, int* __restrict__ tails, int e4) {
    __shared__ int lcount, gbase;
    __shared__ int buf[1024];
    if (threadIdx.x == 0) {
        lcount = 0;
        if (blockIdx.x == 0) tails[4] = tails[3];   // snapshot r2c (tails[3] idle now)
    }
    __syncthreads();
    int lane = threadIdx.x & 63;
    int i = blockIdx.x * blockDim.x + threadIdx.x;
    int4 r = make_int4(-1, -1, -1, -1);
    if (i < e4) r = w_rows4[i];
    int rr[4] = {r.x, r.y, r.z, r.w};
    unsigned fb[4];
#pragma unroll
    for (int j = 0; j < 4; ++j)
        fb[j] = (rr[j] >= 0) ? ((bitsRS[rr[j] >> 5] >> (rr[j] & 31)) & 1u) : 0u;
    bool anyf = (fb[0] | fb[1] | fb[2] | fb[3]) != 0u;
    int4 c = make_int4(0, 0, 0, 0);
    if (anyf) c = w_cols4[i];
    int cc[4] = {c.x, c.y, c.z, c.w};
#pragma unroll
    for (int j = 0; j < 4; ++j) {
        bool isnew = false;
        int n = 0;
        if (fb[j]) {
            n = cc[j];
            unsigned m = 1u << (n & 31);
            unsigned old = atomicOr(&bitsN1[n >> 5], m);
            isnew = (old & m) == 0u;
        }
        unsigned long long mb = __ballot(isnew);
        if (mb) {
            int leader = __ffsll(mb) - 1;
            int b0 = 0;
            if (lane == leader) b0 = atomicAdd(&lcount, __popcll(mb));
            b0 = __shfl(b0, leader);
            if (isnew) {
                int p = b0 + __popcll(mb & ((1ull << lane) - 1));
                if (p < 1024) buf[p] = n;
            }
        }
    }
    __syncthreads();
    int lc = lcount; if (lc > 1024) lc = 1024;
    if (threadIdx.x == 0) gbase = atomicAdd(&tails[2], lc);
    __syncthreads();
    for (int t = threadIdx.x; t < lc; t += blockDim.x) {
        int slot = gbase + t;
        if (slot < N1_CAP) n1slot[buf[t]] = slot;
    }
}

// ---- scanC: wi edges with node-row in n1 -> wi-place + r1 slots (block-agg) ----
__global__ void scanC(const int4* __restrict__ wi_rows4, const int4* __restrict__ wi_cols4,
                      const float4* __restrict__ wi_val4, const float* __restrict__ diag1,
                      const unsigned* __restrict__ bitsN1, const int* __restrict__ n1slot,
                      unsigned* __restrict__ bitsRS, int* __restrict__ rslot,
                      int* __restrict__ slotrow, int* __restrict__ wi_cntC,
                      int2* __restrict__ wi_pairs, int* __restrict__ tails, int e4) {
    __shared__ int lcount, gbase;
    __shared__ int buf[1024];
    if (threadIdx.x == 0) lcount = 0;
    __syncthreads();
    int lane = threadIdx.x & 63;
    int i = blockIdx.x * blockDim.x + threadIdx.x;
    int4 r = make_int4(-1, -1, -1, -1);
    if (i < e4) r = wi_rows4[i];
    int rr[4] = {r.x, r.y, r.z, r.w};
    unsigned fb[4];
#pragma unroll
    for (int j = 0; j < 4; ++j)
        fb[j] = (rr[j] >= 0) ? ((bitsN1[rr[j] >> 5] >> (rr[j] & 31)) & 1u) : 0u;
    bool anyf = (fb[0] | fb[1] | fb[2] | fb[3]) != 0u;
    int4 c = make_int4(0, 0, 0, 0);
    float4 v = make_float4(0.f, 0.f, 0.f, 0.f);
    if (anyf) { c = wi_cols4[i]; v = wi_val4[i]; }
    int cc[4] = {c.x, c.y, c.z, c.w};
    float vv[4] = {v.x, v.y, v.z, v.w};
#pragma unroll
    for (int j = 0; j < 4; ++j) {
        bool isnew = false;
        int col = 0;
        if (fb[j]) {
            col = cc[j];
            float cf = vv[j] * diag1[col];
            int slot = n1slot[rr[j]];
            if (slot >= 0 && slot < N1_CAP) {
                int pos = atomicAdd(&wi_cntC[slot], 1);
                if (pos < WIDEG)
                    wi_pairs[(size_t)slot * WIDEG + pos] =
                        make_int2(col, __float_as_int(cf));
            }
            unsigned m = 1u << (col & 31);
            unsigned old = atomicOr(&bitsRS[col >> 5], m);
            isnew = (old & m) == 0u;
        }
        unsigned long long mb = __ballot(isnew);
        if (mb) {
            int leader = __ffsll(mb) - 1;
            int b0 = 0;
            if (lane == leader) b0 = atomicAdd(&lcount, __popcll(mb));
            b0 = __shfl(b0, leader);
            if (isnew) {
                int p = b0 + __popcll(mb & ((1ull << lane) - 1));
                if (p < 1024) buf[p] = col;
            }
        }
    }
    __syncthreads();
    int lc = lcount; if (lc > 1024) lc = 1024;
    if (threadIdx.x == 0) gbase = atomicAdd(&tails[3], lc);
    __syncthreads();
    for (int t = threadIdx.x; t < lc; t += blockDim.x) {
        int col = buf[t];
        int s = gbase + t;
        if (s < RS_CAP) { rslot[col] = s; slotrow[s] = col; }
    }
}

// ---- scanD: w edges with slotted row (r1|r2) -> compact w-slab place ----
__global__ void scanD(const int4* __restrict__ w_rows4, const int4* __restrict__ w_cols4,
                      const float4* __restrict__ w_val4,
                      const unsigned* __restrict__ bitsRS, const int* __restrict__ rslot,
                      int* __restrict__ w_cntC, int2* __restrict__ w_pairs, int e4) {
    int i = blockIdx.x * blockDim.x + threadIdx.x;
    if (i >= e4) return;
    int4 r = w_rows4[i];
    int rr[4] = {r.x, r.y, r.z, r.w};
    unsigned fb[4];
#pragma unroll
    for (int j = 0; j < 4; ++j) fb[j] = (bitsRS[rr[j] >> 5] >> (rr[j] & 31)) & 1u;
    if (!(fb[0] | fb[1] | fb[2] | fb[3])) return;
    int4 c = w_cols4[i];
    float4 v = w_val4[i];
    int cc[4] = {c.x, c.y, c.z, c.w};
    float vv[4] = {v.x, v.y, v.z, v.w};
    int s[4];
#pragma unroll
    for (int j = 0; j < 4; ++j) s[j] = fb[j] ? rslot[rr[j]] : RS_CAP;
#pragma unroll
    for (int j = 0; j < 4; ++j) {
        if (fb[j] && s[j] < RS_CAP) {
            int pos = atomicAdd(&w_cntC[s[j]], 1);
            if (pos < WDEG)
                w_pairs[(size_t)s[j] * WDEG + pos] =
                    make_int2(cc[j], __float_as_int(vv[j]));
        }
    }
}

// ---- gather_t1: per slot, t1C[s] = sum_w v * x[col]  (32 threads/slot) ----
__global__ void gather_t1(const float* __restrict__ x, float* __restrict__ t1C,
                          const int* __restrict__ w_cntC, const int2* __restrict__ w_pairs,
                          const int* __restrict__ tails) {
    int tot = tails[3]; if (tot > RS_CAP) tot = RS_CAP;
    int total = tot * 32;
    int gstride = gridDim.x * blockDim.x;
    for (int idx = blockIdx.x * blockDim.x + threadIdx.x; idx < total; idx += gstride) {
        int s = idx >> 5;
        int rem = idx & 31;
        int c4 = rem & 7;
        int b = rem >> 3;
        int L = w_cntC[s]; if (L > WDEG) L = WDEG;
        const int2* pr = w_pairs + (size_t)s * WDEG;
        const float4* sb = (const float4*)x + (size_t)b * N * 8 + c4;
        float4 acc = make_float4(0.f, 0.f, 0.f, 0.f);
        int i = 0;
        int L4 = L & ~3;
        for (; i < L4; i += 4) {
            int2 p0 = pr[i + 0];
            int2 p1 = pr[i + 1];
            int2 p2 = pr[i + 2];
            int2 p3 = pr[i + 3];
            float4 s0 = sb[(size_t)p0.x * 8];
            float4 s1 = sb[(size_t)p1.x * 8];
            float4 s2 = sb[(size_t)p2.x * 8];
            float4 s3 = sb[(size_t)p3.x * 8];
            float v0 = __int_as_float(p0.y), v1 = __int_as_float(p1.y);
            float v2 = __int_as_float(p2.y), v3 = __int_as_float(p3.y);
            acc.x += v0 * s0.x + v1 * s1.x + v2 * s2.x + v3 * s3.x;
            acc.y += v0 * s0.y + v1 * s1.y + v2 * s2.y + v3 * s3.y;
            acc.z += v0 * s0.z + v1 * s1.z + v2 * s2.z + v3 * s3.z;
            acc.w += v0 * s0.w + v1 * s1.w + v2 * s2.w + v3 * s3.w;
        }
        for (; i < L; ++i) {
            int2 p = pr[i];
            float4 sv = sb[(size_t)p.x * 8];
            float v = __int_as_float(p.y);
            acc.x += v * sv.x; acc.y += v * sv.y; acc.z += v * sv.z; acc.w += v * sv.w;
        }
        ((float4*)t1C)[(size_t)s * 32 + b * 8 + c4] = acc;
    }
}

// ---- x1mlp: per n1 slot, u = wi-agg(t1C); h2C = lrelu(u@W1)@W2 ----
__global__ void __launch_bounds__(256) x1mlp(
        const float* __restrict__ W1, const float* __restrict__ W2,
        const int* __restrict__ tails,
        const int* __restrict__ wi_cntC, const int2* __restrict__ wi_pairs,
        const int* __restrict__ rslot, const float* __restrict__ t1C,
        float* __restrict__ h2C) {
    __shared__ float W1s[1024], W2s[512];
    __shared__ float uls[8][128];
    __shared__ float ufin[128], x1ls[128];
    for (int i = threadIdx.x; i < 1024; i += 256) W1s[i] = W1[i];
    for (int i = threadIdx.x; i < 512; i += 256) W2s[i] = W2[i];
    int n1c = tails[2]; if (n1c > N1_CAP) n1c = N1_CAP;
    int g = threadIdx.x >> 5, t32 = threadIdx.x & 31;
    int b = t32 >> 3, c4 = t32 & 7;
    const float4* t1f4 = (const float4*)t1C;
    for (int s = blockIdx.x; s < n1c; s += gridDim.x) {
        int L = wi_cntC[s]; if (L > WIDEG) L = WIDEG;
        const int2* wip = wi_pairs + (size_t)s * WIDEG;
        float4 acc = make_float4(0.f, 0.f, 0.f, 0.f);
        for (int e = g; e < L; e += 8) {
            int2 pe = wip[e];
            int rs = rslot[pe.x];
            float coef = __int_as_float(pe.y);        // diag1 already folded
            if (rs < RS_CAP) {
                float4 tv = t1f4[(size_t)rs * 32 + b * 8 + c4];
                acc.x += coef * tv.x; acc.y += coef * tv.y;
                acc.z += coef * tv.z; acc.w += coef * tv.w;
            }
        }
        float* up = &uls[g][b * 32 + c4 * 4];
        up[0] = acc.x; up[1] = acc.y; up[2] = acc.z; up[3] = acc.w;
        __syncthreads();
        if (threadIdx.x < 128) {
            float sum = 0.f;
#pragma unroll
            for (int gg = 0; gg < 8; ++gg) sum += uls[gg][threadIdx.x];
            ufin[threadIdx.x] = sum;
        }
        __syncthreads();
        if (threadIdx.x < 128) {
            int bb = threadIdx.x >> 5, c = threadIdx.x & 31;
            const float* ur = &ufin[bb * 32];
            float o = 0.f;
#pragma unroll
            for (int k = 0; k < 32; ++k) o += ur[k] * W1s[k * 32 + c];
            x1ls[threadIdx.x] = o > 0.f ? o : NEG_SLOPE * o;
        }
        __syncthreads();
        if (threadIdx.x < 64) {
            int bb = threadIdx.x >> 4, c = threadIdx.x & 15;
            const float* xr = &x1ls[bb * 32];
            float o = 0.f;
#pragma unroll
            for (int k = 0; k < 32; ++k) o += xr[k] * W2s[k * 16 + c];
            h2C[(size_t)s * 64 + bb * 16 + c] = o;
        }
        __syncthreads();
    }
}

// ---- t2 gather (r2 slots) + x2 accumulation + heads, ONE block of 1024 ----
__global__ void t2x2heads(const float* __restrict__ h2C,
                          const int* __restrict__ w_cntC, const int2* __restrict__ w_pairs,
                          const int* __restrict__ n1slot, const int* __restrict__ rslot,
                          const int* __restrict__ tails, float* __restrict__ t2C,
                          const int2* __restrict__ x2list,
                          const float* __restrict__ diag2,
                          const float* __restrict__ rw1, const float* __restrict__ rb1,
                          const float* __restrict__ rw2, const float* __restrict__ rb2,
                          float* __restrict__ out) {
    // phase 1: t2 over r2 slots [0, r2c), 16 float4-lanes per slot
    int r2c = tails[4]; if (r2c > R2_CAP) r2c = R2_CAP;
    for (int idx = threadIdx.x; idx < r2c * 16; idx += blockDim.x) {
        int s = idx >> 4;
        int rem = idx & 15;
        int c4 = rem & 3;
        int b = rem >> 2;
        int L = w_cntC[s]; if (L > WDEG) L = WDEG;
        const int2* pr = w_pairs + (size_t)s * WDEG;
        const float4* sb = (const float4*)h2C + b * 4 + c4;
        float4 acc = make_float4(0.f, 0.f, 0.f, 0.f);
        for (int i = 0; i < L; ++i) {
            int2 p = pr[i];
            int hs = n1slot[p.x];               // col is n1 by construction
            float v = __int_as_float(p.y);
            if (hs >= 0 && hs < N1_CAP) {
                float4 sv = sb[(size_t)hs * 16];
                acc.x += v * sv.x; acc.y += v * sv.y; acc.z += v * sv.z; acc.w += v * sv.w;
            }
        }
        ((float4*)t2C)[(size_t)s * 16 + b * 4 + c4] = acc;
    }
    __syncthreads();

    // phase 2: x2 accumulation, edge-parallel across 16 groups of 64 lanes
    int cnt = tails[0]; if (cnt > X2_CAP) cnt = X2_CAP;
    int g = threadIdx.x >> 6, l = threadIdx.x & 63;
    int b = l >> 4, c = l & 15;
    float a0 = 0.f, a1 = 0.f;
    for (int i = g; i < cnt; i += 16) {
        int2 rec = x2list[i];
        int col = rec.x >> 1;
        int s = rslot[col];
        float coef = __int_as_float(rec.y) * diag2[col];
        float v = (s < R2_CAP) ? t2C[(size_t)s * 64 + b * 16 + c] * coef : 0.f;
        if (rec.x & 1) a1 += v; else a0 += v;
    }
    __shared__ float red0[16][64], red1[16][64], xs[2][64];
    red0[g][l] = a0; red1[g][l] = a1;
    __syncthreads();
    if (threadIdx.x < 64) {
        float s0 = 0.f, s1 = 0.f;
#pragma unroll
        for (int gg = 0; gg < 16; ++gg) { s0 += red0[gg][threadIdx.x]; s1 += red1[gg][threadIdx.x]; }
        xs[0][threadIdx.x] = s0; xs[1][threadIdx.x] = s1;
    }
    __syncthreads();
    if (threadIdx.x < 8) {
        int bb = threadIdx.x >> 1, which = threadIdx.x & 1;
        const float* w = which ? rw2 : rw1;
        float acc = which ? rb2[0] : rb1[0];
        for (int k = 0; k < 16; ++k) {
            float xv = xs[which][bb * 16 + k];
            xv = xv > 0.f ? xv : NEG_SLOPE * xv;
            acc += xv * w[k];
        }
        out[bb * 2 + which] = acc;
    }
}

extern "C" void kernel_launch(void* const* d_in, const int* in_sizes, int n_in,
                              void* d_out, int out_size, void* d_ws, size_t ws_size,
                              hipStream_t stream) {
    const int*   w_rows  = (const int*)d_in[0];
    const int*   w_cols  = ((const int*)d_in[0]) + E;
    const float* w_val   = (const float*)d_in[1];
    const int*   wi_rows = (const int*)d_in[2];
    const int*   wi_cols = ((const int*)d_in[2]) + E;
    const float* wi_val  = (const float*)d_in[3];
    const float* x       = (const float*)d_in[4];
    const float* W1      = (const float*)d_in[5];
    const float* diag1   = (const float*)d_in[6];
    const float* W2      = (const float*)d_in[7];
    const float* diag2   = (const float*)d_in[8];
    const float* rw1     = (const float*)d_in[9];
    const float* rb1     = (const float*)d_in[10];
    const float* rw2     = (const float*)d_in[11];
    const float* rb2     = (const float*)d_in[12];
    float* out = (float*)d_out;

    // ---------------- workspace layout (~56 MB) ----------------
    float* t1C = (float*)d_ws;                       // [RS_CAP][128] (25.2 MB)
    float* h2C = t1C + (size_t)RS_CAP * 128;         // [N1_CAP][64]  (1 MB)
    float* t2C = h2C + (size_t)N1_CAP * 64;          // [R2_CAP][64]  (1 MB)
    int* ip = (int*)(t2C + (size_t)R2_CAP * 64);
    // zeroed block (contiguous, ZWORDS words):
    int* w_cntC  = ip; ip += RS_CAP;
    int* wi_cntC = ip; ip += N1_CAP;
    unsigned* bitsRS = (unsigned*)ip; ip += RBW;
    unsigned* bitsN1 = (unsigned*)ip; ip += NBW;
    int* tails = ip; ip += 8;
    // un-zeroed:
    int* rslot   = ip; ip += R;
    int* slotrow = ip; ip += RS_CAP;
    int* n1slot  = ip; ip += N;
    int2* x2list = (int2*)ip; ip += 2 * X2_CAP;
    int2* w_pairs  = (int2*)ip; ip += 2 * (size_t)RS_CAP * WDEG;   // 25.2 MB
    int2* wi_pairs = (int2*)ip; ip += 2 * (size_t)N1_CAP * WIDEG;  // 3.1 MB

    const int e4 = E / 4;
    const int blk = 256;
    const int scanGrid = (e4 + blk - 1) / blk;

    (void)hipMemsetAsync(w_cntC, 0, (size_t)ZWORDS * sizeof(int), stream);

    scanA<<<scanGrid, blk, 0, stream>>>((const int4*)wi_rows, (const int4*)wi_cols,
                                        (const float4*)wi_val, bitsRS, rslot, slotrow,
                                        x2list, tails, e4);
    scanB<<<scanGrid, blk, 0, stream>>>((const int4*)w_rows, (const int4*)w_cols,
                                        bitsRS, bitsN1, n1slot, tails, e4);
    scanC<<<scanGrid, blk, 0, stream>>>((const int4*)wi_rows, (const int4*)wi_cols,
                                        (const float4*)wi_val, diag1, bitsN1, n1slot,
                                        bitsRS, rslot, slotrow, wi_cntC, wi_pairs,
                                        tails, e4);
    scanD<<<scanGrid, blk, 0, stream>>>((const int4*)w_rows, (const int4*)w_cols,
                                        (const float4*)w_val, bitsRS, rslot,
                                        w_cntC, w_pairs, e4);
    gather_t1<<<2048, blk, 0, stream>>>(x, t1C, w_cntC, w_pairs, tails);
    x1mlp<<<1024, blk, 0, stream>>>(W1, W2, tails, wi_cntC, wi_pairs,
                                    rslot, t1C, h2C);
    t2x2heads<<<1, 1024, 0, stream>>>(h2C, w_cntC, w_pairs, n1slot, rslot, tails,
                                      t2C, x2list, diag2, rw1, rb1, rw2, rb2, out);
}